// Round 12
// baseline (7191.475 us; speedup 1.0000x reference)
//
#include <hip/hip_runtime.h>

typedef _Float16 f16;
typedef _Float16 f16x2 __attribute__((ext_vector_type(2)));
typedef _Float16 f16x4 __attribute__((ext_vector_type(4)));
typedef _Float16 f16x8 __attribute__((ext_vector_type(8)));
typedef float f32x4 __attribute__((ext_vector_type(4)));

#define AS1 __attribute__((address_space(1)))
#define AS3 __attribute__((address_space(3)))

static __device__ __forceinline__ float sigf(float x) { return 1.f / (1.f + __expf(-x)); }
static __device__ __forceinline__ float tanh_f(float x) { return 2.f / (1.f + __expf(-2.f * x)) - 1.f; }

// ---------------- fp32 -> fp16 ----------------
__global__ void f2h_kernel(const float* __restrict__ in, f16* __restrict__ out, int n4) {
  const int i = blockIdx.x * blockDim.x + threadIdx.x;
  if (i >= n4) return;
  const float4 v = ((const float4*)in)[i];
  f16x4 o;
  o[0] = (f16)v.x; o[1] = (f16)v.y; o[2] = (f16)v.z; o[3] = (f16)v.w;
  ((f16x4*)out)[i] = o;
}

__global__ void bias_kernel(const float* __restrict__ a, const float* __restrict__ b,
                            float* __restrict__ o, int n) {
  const int i = blockIdx.x * blockDim.x + threadIdx.x;
  if (i < n) o[i] = a[i] + b[i];
}

// ---------------- xg GEMM:  out[dir][row][g] = A[row,:]·Bt[dir*2048+g,:] + bias ----------------
__global__ __launch_bounds__(256) void gemm_xg(const f16* __restrict__ A,
                                               const f16* __restrict__ Bt,
                                               const float* __restrict__ bias,
                                               f16* __restrict__ outp, int K) {
  __shared__ f16 As[128 * 64];
  __shared__ f16 Bs[128 * 64];
  const int tid = threadIdx.x;
  const int w = tid >> 6, l = tid & 63;
  const int m0 = blockIdx.x << 7, n0 = blockIdx.y << 7;
  const int wm = w >> 1, wn = w & 1;
  f32x4 acc[4][4] = {};

  const int lr8 = l >> 3, lc8 = l & 7;
  const int gcol = (lc8 ^ lr8) << 3;

  for (int k0 = 0; k0 < K; k0 += 64) {
    __syncthreads();
#pragma unroll
    for (int j = 0; j < 4; ++j) {
      const int i = (w << 2) + j;
      const f16* ga = A + (size_t)(m0 + (i << 3) + lr8) * K + (k0 + gcol);
      __builtin_amdgcn_global_load_lds((const AS1 void*)ga, (AS3 void*)(As + (i << 9)), 16, 0, 0);
      const f16* gb = Bt + (size_t)(n0 + (i << 3) + lr8) * K + (k0 + gcol);
      __builtin_amdgcn_global_load_lds((const AS1 void*)gb, (AS3 void*)(Bs + (i << 9)), 16, 0, 0);
    }
    asm volatile("s_waitcnt vmcnt(0)" ::: "memory");
    __syncthreads();

#pragma unroll
    for (int kk = 0; kk < 2; ++kk) {
      const int cb = (kk << 6) + ((l >> 4) << 4);
      f16x8 af[4], bf[4];
#pragma unroll
      for (int a = 0; a < 4; ++a) {
        const int r = (wm << 6) + (a << 4) + (l & 15);
        af[a] = *(const f16x8*)((const char*)As + r * 128 + (cb ^ ((r & 7) << 4)));
      }
#pragma unroll
      for (int b = 0; b < 4; ++b) {
        const int r = (wn << 6) + (b << 4) + (l & 15);
        bf[b] = *(const f16x8*)((const char*)Bs + r * 128 + (cb ^ ((r & 7) << 4)));
      }
#pragma unroll
      for (int a = 0; a < 4; ++a)
#pragma unroll
        for (int b = 0; b < 4; ++b)
          acc[a][b] = __builtin_amdgcn_mfma_f32_16x16x32_f16(af[a], bf[b], acc[a][b], 0, 0, 0);
    }
  }

#pragma unroll
  for (int b = 0; b < 4; ++b) {
    const int col = n0 + (wn << 6) + (b << 4) + (l & 15);
    const float bv = bias[col];
    f16* ob = outp + (size_t)(col >> 11) * (16384ull * 2048) + (col & 2047);
#pragma unroll
    for (int a = 0; a < 4; ++a) {
      const int row0 = m0 + (wm << 6) + (a << 4) + ((l >> 4) << 2);
#pragma unroll
      for (int r = 0; r < 4; ++r)
        ob[(size_t)(row0 + r) * 2048] = (f16)(acc[a][b][r] + bv);
    }
  }
}

// ---------------- persistent bidirectional LSTM scan (one layer) ----------------
// grid: 64 WGs = 2 dirs x 32 unit-slices. Wh slice in LDS. R3/R11 ring protocol:
// 8B {tag=epoch, data} entries, 4-slot ring, bounded guards, no fences.
// R12: depth-2 GROUP PIPELINE. Batch rows 0-15 (g0) and 16-31 (g1) are INDEPENDENT
// recurrence chains. Per t: phase(g0) then phase(g1). Each phase consumes a burst
// PRE-ISSUED in the previous phase (ages through the other group's compute), so a
// group's publish->consume wall-gap spans a full opposite phase: step -> W + c.
// Phase: sentinel+flat on saved burst -> stage 16 rows -> xg(active waves) ->
// issue next burst -> barrier -> MFMA[16x512x64] -> G write -> barrier -> cell/publish.
__global__ __launch_bounds__(256) void lstm_scan(const f16* __restrict__ Whb,   // [2][2048][512]
                                                 const f16* __restrict__ xg,    // [2][16384][2048]
                                                 unsigned long long* __restrict__ ring,  // [2][4][32][256]
                                                 f16* __restrict__ h0_all,      // [16384][1024] (layer0)
                                                 float* __restrict__ outf,      // [16384][1024] (layer1)
                                                 float* __restrict__ hn,        // [4][32][512]
                                                 float* __restrict__ cn,        // [4][32][512]
                                                 const int layer) {
  __shared__ f16 Wh_s[64 * 512];      // 64 KB, XOR-swizzled rows
  __shared__ f16 h_s[16 * 512];       // 16 KB: one group's rows (reuse safe per barriers)
  __shared__ float G_s[4 * 32 * 18];  // 9 KB gate exchange (rows 0..15 used)

  const int tid = threadIdx.x;
  const int dir = blockIdx.x >> 5;
  const int s = blockIdx.x & 31;
  const int w = tid >> 6, l = tid & 63;

  // load Wh slice: local row lr=16g+u <- Whb row dir*2048 + 512g + 16s + u (wave-coalesced)
#pragma unroll
  for (int j = 0; j < 16; ++j) {
    const int chunk = (j << 8) + tid;
    const int lr = chunk >> 6;
    const int cbyte = (chunk & 63) << 4;
    const int g = lr >> 4, u = lr & 15;
    const char* src = (const char*)Whb + (((size_t)dir * 2048 + (g << 9) + (s << 4) + u) << 10) + cbyte;
    const uint4 v = *(const uint4*)src;
    *(uint4*)((char*)Wh_s + (lr << 10) + (cbyte ^ ((lr & 7) << 4))) = v;
  }

  unsigned long long* rdir = ring + ((size_t)dir << 15);  // 4*32*256 entries per dir
  const int bb = tid >> 3;   // global batch row 0..31 (my cell ownership)
  const int up = tid & 7;    // unit pair -> units 2up, 2up+1
  const int myg = bb >> 4;   // my group (0: rows 0-15, 1: rows 16-31) — wave-uniform

  float c0 = 0.f, c1 = 0.f;
  __syncthreads();

  // ---------------- prologue: t=0 (xg only), publish tag 1 for both groups ----------------
  {
    const int tau0 = dir ? 511 : 0;
    const f16* xr = xg + (((size_t)dir * 16384 + (size_t)bb * 512 + tau0) << 11) + (s << 4) + (up << 1);
    const f16x2 xv0 = *(const f16x2*)(xr);
    const f16x2 xv1 = *(const f16x2*)(xr + 512);
    const f16x2 xv2 = *(const f16x2*)(xr + 1024);
    const f16x2 xv3 = *(const f16x2*)(xr + 1536);
    const float i0 = sigf((float)xv0[0]), i1 = sigf((float)xv0[1]);
    const float f0 = sigf((float)xv1[0]), f1 = sigf((float)xv1[1]);
    const float g0 = tanh_f((float)xv2[0]), g1 = tanh_f((float)xv2[1]);
    const float o0 = sigf((float)xv3[0]), o1 = sigf((float)xv3[1]);
    c0 = i0 * g0;
    c1 = i1 * g1;
    const float h0v = o0 * tanh_f(c0);
    const float h1v = o1 * tanh_f(c1);
    union { f16x2 h2; unsigned u; } pk;
    pk.h2[0] = (f16)h0v; pk.h2[1] = (f16)h1v;
    const size_t ridx = ((size_t)1 << 13) + ((size_t)bb << 8) + (s << 3) + up;
    const unsigned long long pv = ((unsigned long long)pk.u << 32) | 1ull;
    __hip_atomic_store(rdir + ridx, pv, __ATOMIC_RELAXED, __HIP_MEMORY_SCOPE_AGENT);
    const size_t orow = (((size_t)bb * 512 + (size_t)tau0) << 10) + ((size_t)dir << 9) + (s << 4) + (up << 1);
    if (layer == 0) *(unsigned*)(h0_all + orow) = pk.u;
    else            *(float2*)(outf + orow) = make_float2(h0v, h1v);
  }

  // pre-issue burst for (g0, t=1): 16 entries/thread in 4 chunks of 4
  unsigned long long sv[4][4];
  {
    const unsigned long long* nb = rdir + ((size_t)1 << 13);  // slot 1, group 0 base
#pragma unroll
    for (int j = 0; j < 4; ++j) {
      const unsigned long long* sp = nb + (((j << 8) + tid) << 2);
#pragma unroll
      for (int q = 0; q < 4; ++q)
        sv[j][q] = __hip_atomic_load(sp + q, __ATOMIC_RELAXED, __HIP_MEMORY_SCOPE_AGENT);
    }
  }

#pragma unroll 1
  for (int t = 1; t < 512; ++t) {
    const int tau = dir ? (511 - t) : t;
#pragma unroll
    for (int gp = 0; gp < 2; ++gp) {
      const unsigned tgt = (unsigned)t;
      const unsigned long long* gb = rdir + ((size_t)(t & 3) << 13) + (gp << 12);

      // (1) sentinel: spin on chunk 0 of the saved burst
      {
        const unsigned long long* sp = gb + (tid << 2);
        int guard = 0;
        while (!(((unsigned)sv[0][0] == tgt) & ((unsigned)sv[0][1] == tgt) &
                 ((unsigned)sv[0][2] == tgt) & ((unsigned)sv[0][3] == tgt))) {
#pragma unroll
          for (int q = 0; q < 4; ++q)
            sv[0][q] = __hip_atomic_load(sp + q, __ATOMIC_RELAXED, __HIP_MEMORY_SCOPE_AGENT);
          if (++guard > (1 << 20)) break;
        }
      }
      // (2) flat verify chunks 1..3 (re-issue stale concurrently; rare)
      {
        bool ok1 = (((unsigned)sv[1][0] == tgt) & ((unsigned)sv[1][1] == tgt) &
                    ((unsigned)sv[1][2] == tgt) & ((unsigned)sv[1][3] == tgt));
        bool ok2 = (((unsigned)sv[2][0] == tgt) & ((unsigned)sv[2][1] == tgt) &
                    ((unsigned)sv[2][2] == tgt) & ((unsigned)sv[2][3] == tgt));
        bool ok3 = (((unsigned)sv[3][0] == tgt) & ((unsigned)sv[3][1] == tgt) &
                    ((unsigned)sv[3][2] == tgt) & ((unsigned)sv[3][3] == tgt));
        int guard = 0;
        while ((!ok1 || !ok2 || !ok3) && ++guard <= (1 << 20)) {
          if (!ok1) {
            const unsigned long long* sp = gb + (((1 << 8) + tid) << 2);
#pragma unroll
            for (int q = 0; q < 4; ++q)
              sv[1][q] = __hip_atomic_load(sp + q, __ATOMIC_RELAXED, __HIP_MEMORY_SCOPE_AGENT);
          }
          if (!ok2) {
            const unsigned long long* sp = gb + (((2 << 8) + tid) << 2);
#pragma unroll
            for (int q = 0; q < 4; ++q)
              sv[2][q] = __hip_atomic_load(sp + q, __ATOMIC_RELAXED, __HIP_MEMORY_SCOPE_AGENT);
          }
          if (!ok3) {
            const unsigned long long* sp = gb + (((3 << 8) + tid) << 2);
#pragma unroll
            for (int q = 0; q < 4; ++q)
              sv[3][q] = __hip_atomic_load(sp + q, __ATOMIC_RELAXED, __HIP_MEMORY_SCOPE_AGENT);
          }
          ok1 = (((unsigned)sv[1][0] == tgt) & ((unsigned)sv[1][1] == tgt) &
                 ((unsigned)sv[1][2] == tgt) & ((unsigned)sv[1][3] == tgt));
          ok2 = (((unsigned)sv[2][0] == tgt) & ((unsigned)sv[2][1] == tgt) &
                 ((unsigned)sv[2][2] == tgt) & ((unsigned)sv[2][3] == tgt));
          ok3 = (((unsigned)sv[3][0] == tgt) & ((unsigned)sv[3][1] == tgt) &
                 ((unsigned)sv[3][2] == tgt) & ((unsigned)sv[3][3] == tgt));
        }
      }
      // (3) stage 16 group rows to h_s (XOR-swizzled)
#pragma unroll
      for (int j = 0; j < 4; ++j) {
        const int idx = (j << 8) + tid;
        const int r = idx >> 6;  // group-local row 0..15
        uint4 d;
        d.x = (unsigned)(sv[j][0] >> 32);
        d.y = (unsigned)(sv[j][1] >> 32);
        d.z = (unsigned)(sv[j][2] >> 32);
        d.w = (unsigned)(sv[j][3] >> 32);
        const int cbyte = (idx & 63) << 4;
        *(uint4*)((char*)h_s + (r << 10) + (cbyte ^ ((r & 7) << 4))) = d;
      }

      // (4) xg loads for this group's cells (active waves only; wave-uniform)
      const bool act = (myg == gp);
      f16x2 xv0 = {}, xv1 = {}, xv2 = {}, xv3 = {};
      if (act) {
        const f16* xr = xg + (((size_t)dir * 16384 + (size_t)bb * 512 + (size_t)tau) << 11) + (s << 4) + (up << 1);
        xv0 = *(const f16x2*)(xr);
        xv1 = *(const f16x2*)(xr + 512);
        xv2 = *(const f16x2*)(xr + 1024);
        xv3 = *(const f16x2*)(xr + 1536);
      }

      // (5) pre-issue burst for the next phase's group: (g1,t) or (g0,t+1)
      {
        const int ot = gp ? (t + 1) : t;
        const unsigned long long* nb = rdir + ((size_t)(ot & 3) << 13) + ((gp ^ 1) << 12);
#pragma unroll
        for (int j = 0; j < 4; ++j) {
          const unsigned long long* sp = nb + (((j << 8) + tid) << 2);
#pragma unroll
          for (int q = 0; q < 4; ++q)
            sv[j][q] = __hip_atomic_load(sp + q, __ATOMIC_RELAXED, __HIP_MEMORY_SCOPE_AGENT);
        }
      }

      __syncthreads();  // staging visible

      // (6) MFMA: G[r(16), 16w+u] = sum_k h[r,k] * WhS[16w+u, k] (wave w owns gate w)
      f32x4 acc0 = {};
#pragma unroll
      for (int kk = 0; kk < 16; ++kk) {
        const int cb = (kk << 6) + ((l >> 4) << 4);
        const int ra0 = l & 15;
        const int rb = (w << 4) + ra0;
        const f16x8 a0 = *(const f16x8*)((const char*)h_s + (ra0 << 10) + (cb ^ ((ra0 & 7) << 4)));
        const f16x8 bv = *(const f16x8*)((const char*)Wh_s + (rb << 10) + (cb ^ ((rb & 7) << 4)));
        acc0 = __builtin_amdgcn_mfma_f32_16x16x32_f16(a0, bv, acc0, 0, 0, 0);
      }
#pragma unroll
      for (int r = 0; r < 4; ++r) {
        const int dr = ((l >> 4) << 2) + r;
        G_s[((w << 5) + dr) * 18 + (l & 15)] = acc0[r];
      }
      __syncthreads();  // G visible (cross-wave gates)

      // (7) cell + publish (this group's two waves)
      if (act) {
        const int rl = bb & 15;
        const float* gpos = G_s + rl * 18 + (up << 1);
        const float2 vi = *(const float2*)(gpos);
        const float2 vf = *(const float2*)(gpos + 576);
        const float2 vg = *(const float2*)(gpos + 1152);
        const float2 vo = *(const float2*)(gpos + 1728);
        const float pi0 = vi.x + (float)xv0[0], pi1 = vi.y + (float)xv0[1];
        const float pf0 = vf.x + (float)xv1[0], pf1 = vf.y + (float)xv1[1];
        const float pg0 = vg.x + (float)xv2[0], pg1 = vg.y + (float)xv2[1];
        const float po0 = vo.x + (float)xv3[0], po1 = vo.y + (float)xv3[1];

        const float i0 = sigf(pi0), i1 = sigf(pi1);
        const float f0 = sigf(pf0), f1 = sigf(pf1);
        const float g0 = tanh_f(pg0), g1 = tanh_f(pg1);
        const float o0 = sigf(po0), o1 = sigf(po1);
        c0 = f0 * c0 + i0 * g0;
        c1 = f1 * c1 + i1 * g1;
        const float h0v = o0 * tanh_f(c0);
        const float h1v = o1 * tanh_f(c1);

        union { f16x2 h2; unsigned u; } pk;
        pk.h2[0] = (f16)h0v; pk.h2[1] = (f16)h1v;

        const size_t ridx = ((size_t)((t + 1) & 3) << 13) + ((size_t)bb << 8) + (s << 3) + up;
        const unsigned long long pv = ((unsigned long long)pk.u << 32) | (unsigned long long)(t + 1);
        __hip_atomic_store(rdir + ridx, pv, __ATOMIC_RELAXED, __HIP_MEMORY_SCOPE_AGENT);

        const size_t orow = (((size_t)bb * 512 + (size_t)tau) << 10) + ((size_t)dir << 9) + (s << 4) + (up << 1);
        if (layer == 0) *(unsigned*)(h0_all + orow) = pk.u;
        else            *(float2*)(outf + orow) = make_float2(h0v, h1v);
        if (t == 511) {
          const size_t nidx = (((size_t)(layer << 1) + (size_t)dir) << 14) + ((size_t)bb << 9) + (s << 4) + (up << 1);
          *(float2*)(hn + nidx) = make_float2(h0v, h1v);
          *(float2*)(cn + nidx) = make_float2(c0, c1);
        }
      }
    }
  }
}

// ---------------- host ----------------
extern "C" void kernel_launch(void* const* d_in, const int* in_sizes, int n_in,
                              void* d_out, int out_size, void* d_ws, size_t ws_size,
                              hipStream_t stream) {
  const float* x = (const float*)d_in[0];
  const float* Wx0 = (const float*)d_in[1];
  const float* Wh0 = (const float*)d_in[2];
  const float* bx0 = (const float*)d_in[3];
  const float* bh0 = (const float*)d_in[4];
  const float* Wx1 = (const float*)d_in[5];
  const float* Wh1 = (const float*)d_in[6];
  const float* bx1 = (const float*)d_in[7];
  const float* bh1 = (const float*)d_in[8];

  char* ws = (char*)d_ws;
  size_t off = 0;
  auto alloc = [&](size_t b) { char* p = ws + off; off += (b + 255) & ~(size_t)255; return p; };
  f16* xg = (f16*)alloc(2ull * 16384 * 2048 * 2);      // 134 MB (reused both layers)
  f16* x_h = (f16*)alloc(16384ull * 512 * 2);
  f16* h0a = (f16*)alloc(16384ull * 1024 * 2);
  f16* Wx0h = (f16*)alloc(2ull * 2048 * 512 * 2);
  f16* Wh0h = (f16*)alloc(2ull * 2048 * 512 * 2);
  f16* Wx1h = (f16*)alloc(2ull * 2048 * 1024 * 2);
  f16* Wh1h = (f16*)alloc(2ull * 2048 * 512 * 2);
  float* bias0 = (float*)alloc(4096 * 4);
  float* bias1 = (float*)alloc(4096 * 4);
  const size_t RB = 2ull * 4 * 32 * 256 * 8;           // 512 KB per layer ring
  unsigned long long* ring0 = (unsigned long long*)alloc(RB);
  unsigned long long* ring1 = (unsigned long long*)alloc(RB);
  if (off > ws_size) return;  // needs ~207 MB of workspace

  float* outp = (float*)d_out;
  float* hn = outp + 16384ull * 1024;
  float* cn = hn + 4ull * 32 * 512;

  // clear ring tags (stale tags from a previous replay would alias epochs)
  hipMemsetAsync(ring0, 0, 2 * RB, stream);

  f2h_kernel<<<dim3(2097152 / 256), 256, 0, stream>>>(x, x_h, 2097152);
  f2h_kernel<<<dim3(524288 / 256), 256, 0, stream>>>(Wx0, Wx0h, 524288);
  f2h_kernel<<<dim3(524288 / 256), 256, 0, stream>>>(Wh0, Wh0h, 524288);
  f2h_kernel<<<dim3(1048576 / 256), 256, 0, stream>>>(Wx1, Wx1h, 1048576);
  f2h_kernel<<<dim3(524288 / 256), 256, 0, stream>>>(Wh1, Wh1h, 524288);
  bias_kernel<<<16, 256, 0, stream>>>(bx0, bh0, bias0, 4096);
  bias_kernel<<<16, 256, 0, stream>>>(bx1, bh1, bias1, 4096);

  dim3 g(128, 32);
  gemm_xg<<<g, 256, 0, stream>>>(x_h, Wx0h, bias0, xg, 512);
  lstm_scan<<<64, 256, 0, stream>>>(Wh0h, xg, ring0, h0a, nullptr, hn, cn, 0);
  gemm_xg<<<g, 256, 0, stream>>>(h0a, Wx1h, bias1, xg, 1024);
  lstm_scan<<<64, 256, 0, stream>>>(Wh1h, xg, ring1, nullptr, outp, hn, cn, 1);
}

// Round 13
// 5135.674 us; speedup vs baseline: 1.4003x; 1.4003x over previous
//
#include <hip/hip_runtime.h>

typedef _Float16 f16;
typedef _Float16 f16x2 __attribute__((ext_vector_type(2)));
typedef _Float16 f16x4 __attribute__((ext_vector_type(4)));
typedef _Float16 f16x8 __attribute__((ext_vector_type(8)));
typedef float f32x4 __attribute__((ext_vector_type(4)));

#define AS1 __attribute__((address_space(1)))
#define AS3 __attribute__((address_space(3)))

static __device__ __forceinline__ float sigf(float x) { return 1.f / (1.f + __expf(-x)); }
static __device__ __forceinline__ float tanh_f(float x) { return 2.f / (1.f + __expf(-2.f * x)) - 1.f; }

// ---------------- fp32 -> fp16 ----------------
__global__ void f2h_kernel(const float* __restrict__ in, f16* __restrict__ out, int n4) {
  const int i = blockIdx.x * blockDim.x + threadIdx.x;
  if (i >= n4) return;
  const float4 v = ((const float4*)in)[i];
  f16x4 o;
  o[0] = (f16)v.x; o[1] = (f16)v.y; o[2] = (f16)v.z; o[3] = (f16)v.w;
  ((f16x4*)out)[i] = o;
}

__global__ void bias_kernel(const float* __restrict__ a, const float* __restrict__ b,
                            float* __restrict__ o, int n) {
  const int i = blockIdx.x * blockDim.x + threadIdx.x;
  if (i < n) o[i] = a[i] + b[i];
}

// ---------------- xg GEMM:  out[dir][row][g] = A[row,:]·Bt[dir*2048+g,:] + bias ----------------
__global__ __launch_bounds__(256) void gemm_xg(const f16* __restrict__ A,
                                               const f16* __restrict__ Bt,
                                               const float* __restrict__ bias,
                                               f16* __restrict__ outp, int K) {
  __shared__ f16 As[128 * 64];
  __shared__ f16 Bs[128 * 64];
  const int tid = threadIdx.x;
  const int w = tid >> 6, l = tid & 63;
  const int m0 = blockIdx.x << 7, n0 = blockIdx.y << 7;
  const int wm = w >> 1, wn = w & 1;
  f32x4 acc[4][4] = {};

  const int lr8 = l >> 3, lc8 = l & 7;
  const int gcol = (lc8 ^ lr8) << 3;

  for (int k0 = 0; k0 < K; k0 += 64) {
    __syncthreads();
#pragma unroll
    for (int j = 0; j < 4; ++j) {
      const int i = (w << 2) + j;
      const f16* ga = A + (size_t)(m0 + (i << 3) + lr8) * K + (k0 + gcol);
      __builtin_amdgcn_global_load_lds((const AS1 void*)ga, (AS3 void*)(As + (i << 9)), 16, 0, 0);
      const f16* gb = Bt + (size_t)(n0 + (i << 3) + lr8) * K + (k0 + gcol);
      __builtin_amdgcn_global_load_lds((const AS1 void*)gb, (AS3 void*)(Bs + (i << 9)), 16, 0, 0);
    }
    asm volatile("s_waitcnt vmcnt(0)" ::: "memory");
    __syncthreads();

#pragma unroll
    for (int kk = 0; kk < 2; ++kk) {
      const int cb = (kk << 6) + ((l >> 4) << 4);
      f16x8 af[4], bf[4];
#pragma unroll
      for (int a = 0; a < 4; ++a) {
        const int r = (wm << 6) + (a << 4) + (l & 15);
        af[a] = *(const f16x8*)((const char*)As + r * 128 + (cb ^ ((r & 7) << 4)));
      }
#pragma unroll
      for (int b = 0; b < 4; ++b) {
        const int r = (wn << 6) + (b << 4) + (l & 15);
        bf[b] = *(const f16x8*)((const char*)Bs + r * 128 + (cb ^ ((r & 7) << 4)));
      }
#pragma unroll
      for (int a = 0; a < 4; ++a)
#pragma unroll
        for (int b = 0; b < 4; ++b)
          acc[a][b] = __builtin_amdgcn_mfma_f32_16x16x32_f16(af[a], bf[b], acc[a][b], 0, 0, 0);
    }
  }

#pragma unroll
  for (int b = 0; b < 4; ++b) {
    const int col = n0 + (wn << 6) + (b << 4) + (l & 15);
    const float bv = bias[col];
    f16* ob = outp + (size_t)(col >> 11) * (16384ull * 2048) + (col & 2047);
#pragma unroll
    for (int a = 0; a < 4; ++a) {
      const int row0 = m0 + (wm << 6) + (a << 4) + ((l >> 4) << 2);
#pragma unroll
      for (int r = 0; r < 4; ++r)
        ob[(size_t)(row0 + r) * 2048] = (f16)(acc[a][b][r] + bv);
    }
  }
}

// ---------------- persistent bidirectional LSTM scan (one layer) ----------------
// grid: 64 WGs = 2 dirs x 32 unit-slices. Wh slice resident in LDS. Ring protocol:
// 8B {tag=epoch, data} entries, 4-slot ring, bounded guards, no fences.
// Poll = sentinel-gated flat verify (best measured: 4.74 us/step):
//  1) burst all 32 entries
//  2) spin ONLY on chunk 0 (sentinels distributed across producers/lines)
//  3) re-issue stale chunks CONCURRENTLY, flat-verify, bounded straggler loop.
// Structural note (R1-R12): the step floor is the cross-XCD publish->visibility
// window (~3.5-4 us through the L3 coherence point) — poll shape, queue hygiene,
// barrier structure, L2 shortcuts, and phase pipelining all probed; none beat this.
__global__ __launch_bounds__(256) void lstm_scan(const f16* __restrict__ Whb,   // [2][2048][512]
                                                 const f16* __restrict__ xg,    // [2][16384][2048]
                                                 unsigned long long* __restrict__ ring,  // [2][4][32][256]
                                                 f16* __restrict__ h0_all,      // [16384][1024] (layer0)
                                                 float* __restrict__ outf,      // [16384][1024] (layer1)
                                                 float* __restrict__ hn,        // [4][32][512]
                                                 float* __restrict__ cn,        // [4][32][512]
                                                 const int layer) {
  __shared__ f16 Wh_s[64 * 512];      // 64 KB, XOR-swizzled rows
  __shared__ f16 h_s[32 * 512];       // 32 KB, XOR-swizzled rows
  __shared__ float G_s[4 * 32 * 18];  // 9 KB gate exchange, stride 18

  const int tid = threadIdx.x;
  const int dir = blockIdx.x >> 5;
  const int s = blockIdx.x & 31;
  const int w = tid >> 6, l = tid & 63;

  // load Wh slice: local row lr=16g+u <- Whb row dir*2048 + 512g + 16s + u (wave-coalesced)
#pragma unroll
  for (int j = 0; j < 16; ++j) {
    const int chunk = (j << 8) + tid;
    const int lr = chunk >> 6;
    const int cbyte = (chunk & 63) << 4;
    const int g = lr >> 4, u = lr & 15;
    const char* src = (const char*)Whb + (((size_t)dir * 2048 + (g << 9) + (s << 4) + u) << 10) + cbyte;
    const uint4 v = *(const uint4*)src;
    *(uint4*)((char*)Wh_s + (lr << 10) + (cbyte ^ ((lr & 7) << 4))) = v;
  }

  unsigned long long* rdir = ring + ((size_t)dir << 15);  // 4*32*256 entries per dir
  const int bb = tid >> 3;  // batch row 0..31
  const int up = tid & 7;   // unit pair -> units 2up, 2up+1

  float c0 = 0.f, c1 = 0.f;
  __syncthreads();

#pragma unroll 1
  for (int t = 0; t < 512; ++t) {
    const int tau = dir ? (511 - t) : t;
    // xg loads at step start
    const f16* xr = xg + (((size_t)dir * 16384 + (size_t)bb * 512 + (size_t)tau) << 11) + (s << 4) + (up << 1);
    const f16x2 xv0 = *(const f16x2*)(xr);
    const f16x2 xv1 = *(const f16x2*)(xr + 512);
    const f16x2 xv2 = *(const f16x2*)(xr + 1024);
    const f16x2 xv3 = *(const f16x2*)(xr + 1536);

    float pi0 = 0.f, pi1 = 0.f, pf0 = 0.f, pf1 = 0.f, pg0 = 0.f, pg1 = 0.f, po0 = 0.f, po1 = 0.f;

    if (t > 0) {
      const unsigned tgt = (unsigned)t;
      const unsigned long long* rs = rdir + ((size_t)(t & 3) << 13);  // slot: 32*256 entries
      unsigned long long v[8][4];
      // (1) optimistic burst: all 32 independent 8B loads
#pragma unroll
      for (int j = 0; j < 8; ++j) {
        const int chunk = (j << 8) + tid;
        const unsigned long long* sp = rs + ((chunk >> 6) << 8) + ((chunk & 63) << 2);
#pragma unroll
        for (int q = 0; q < 4; ++q)
          v[j][q] = __hip_atomic_load(sp + q, __ATOMIC_RELAXED, __HIP_MEMORY_SCOPE_AGENT);
      }
      // (2) sentinel spin: chunk 0 only (covers the visibility window cheaply)
      {
        const unsigned long long* sp = rs + ((tid >> 6) << 8) + ((tid & 63) << 2);
        int guard = 0;
        while (!(((unsigned)v[0][0] == tgt) & ((unsigned)v[0][1] == tgt) &
                 ((unsigned)v[0][2] == tgt) & ((unsigned)v[0][3] == tgt))) {
#pragma unroll
          for (int q = 0; q < 4; ++q)
            v[0][q] = __hip_atomic_load(sp + q, __ATOMIC_RELAXED, __HIP_MEMORY_SCOPE_AGENT);
          if (++guard > (1 << 20)) break;
        }
      }
      // (3) flat verify: re-issue ALL stale chunks concurrently, check, repeat (rare)
      {
        bool ok[8];
        ok[0] = true;
        int remaining = 0;
#pragma unroll
        for (int j = 1; j < 8; ++j) {
          ok[j] = (((unsigned)v[j][0] == tgt) & ((unsigned)v[j][1] == tgt) &
                   ((unsigned)v[j][2] == tgt) & ((unsigned)v[j][3] == tgt));
          remaining += ok[j] ? 0 : 1;
        }
        int guard = 0;
        while (remaining && ++guard <= (1 << 20)) {
#pragma unroll
          for (int j = 1; j < 8; ++j) {
            if (!ok[j]) {
              const int chunk = (j << 8) + tid;
              const unsigned long long* sp = rs + ((chunk >> 6) << 8) + ((chunk & 63) << 2);
#pragma unroll
              for (int q = 0; q < 4; ++q)
                v[j][q] = __hip_atomic_load(sp + q, __ATOMIC_RELAXED, __HIP_MEMORY_SCOPE_AGENT);
            }
          }
#pragma unroll
          for (int j = 1; j < 8; ++j) {
            if (!ok[j]) {
              if (((unsigned)v[j][0] == tgt) & ((unsigned)v[j][1] == tgt) &
                  ((unsigned)v[j][2] == tgt) & ((unsigned)v[j][3] == tgt)) {
                ok[j] = true;
                --remaining;
              }
            }
          }
        }
      }
      // stage to LDS (XOR-swizzled)
#pragma unroll
      for (int j = 0; j < 8; ++j) {
        const int chunk = (j << 8) + tid;
        const int b = chunk >> 6;
        uint4 d;
        d.x = (unsigned)(v[j][0] >> 32);
        d.y = (unsigned)(v[j][1] >> 32);
        d.z = (unsigned)(v[j][2] >> 32);
        d.w = (unsigned)(v[j][3] >> 32);
        const int cbyte = (chunk & 63) << 4;
        *(uint4*)((char*)h_s + (b << 10) + (cbyte ^ ((b & 7) << 4))) = d;
      }
      __syncthreads();

      // G[b, 16w+u] = sum_k h[b,k] * WhS[16w+u, k]   (wave w owns gate w)
      f32x4 acc0 = {}, acc1 = {};
#pragma unroll
      for (int kk = 0; kk < 16; ++kk) {
        const int cb = (kk << 6) + ((l >> 4) << 4);
        const int ra0 = l & 15;
        const int ra1 = 16 + ra0;
        const int rb = (w << 4) + ra0;
        const f16x8 a0 = *(const f16x8*)((const char*)h_s + (ra0 << 10) + (cb ^ ((ra0 & 7) << 4)));
        const f16x8 a1 = *(const f16x8*)((const char*)h_s + (ra1 << 10) + (cb ^ ((ra1 & 7) << 4)));
        const f16x8 bv = *(const f16x8*)((const char*)Wh_s + (rb << 10) + (cb ^ ((rb & 7) << 4)));
        acc0 = __builtin_amdgcn_mfma_f32_16x16x32_f16(a0, bv, acc0, 0, 0, 0);
        acc1 = __builtin_amdgcn_mfma_f32_16x16x32_f16(a1, bv, acc1, 0, 0, 0);
      }
#pragma unroll
      for (int r = 0; r < 4; ++r) {
        const int dr = ((l >> 4) << 2) + r;
        G_s[((w << 5) + dr) * 18 + (l & 15)] = acc0[r];
        G_s[((w << 5) + 16 + dr) * 18 + (l & 15)] = acc1[r];
      }
      __syncthreads();

      const float* gp = G_s + bb * 18 + (up << 1);
      const float2 vi = *(const float2*)(gp);
      const float2 vf = *(const float2*)(gp + 576);
      const float2 vg = *(const float2*)(gp + 1152);
      const float2 vo = *(const float2*)(gp + 1728);
      pi0 = vi.x; pi1 = vi.y; pf0 = vf.x; pf1 = vf.y;
      pg0 = vg.x; pg1 = vg.y; po0 = vo.x; po1 = vo.y;
    }

    pi0 += (float)xv0[0]; pi1 += (float)xv0[1];
    pf0 += (float)xv1[0]; pf1 += (float)xv1[1];
    pg0 += (float)xv2[0]; pg1 += (float)xv2[1];
    po0 += (float)xv3[0]; po1 += (float)xv3[1];

    const float i0 = sigf(pi0), i1 = sigf(pi1);
    const float f0 = sigf(pf0), f1 = sigf(pf1);
    const float g0 = tanh_f(pg0), g1 = tanh_f(pg1);
    const float o0 = sigf(po0), o1 = sigf(po1);
    c0 = f0 * c0 + i0 * g0;
    c1 = f1 * c1 + i1 * g1;
    const float h0v = o0 * tanh_f(c0);
    const float h1v = o1 * tanh_f(c1);

    union { f16x2 h2; unsigned u; } pk;
    pk.h2[0] = (f16)h0v; pk.h2[1] = (f16)h1v;

    // publish h_{t+1}: single 8B atomic {tag = t+1, data} — fire and forget
    {
      const size_t ridx = ((size_t)((t + 1) & 3) << 13) + ((size_t)bb << 8) + (s << 3) + up;
      const unsigned long long pv = ((unsigned long long)pk.u << 32) | (unsigned long long)(t + 1);
      __hip_atomic_store(rdir + ridx, pv, __ATOMIC_RELAXED, __HIP_MEMORY_SCOPE_AGENT);
    }

    // epilogue stores — off the critical path
    const size_t orow = (((size_t)bb * 512 + (size_t)tau) << 10) + ((size_t)dir << 9) + (s << 4) + (up << 1);
    if (layer == 0) {
      *(unsigned*)(h0_all + orow) = pk.u;
    } else {
      *(float2*)(outf + orow) = make_float2(h0v, h1v);
    }
    if (t == 511) {
      const size_t nidx = (((size_t)(layer << 1) + (size_t)dir) << 14) + ((size_t)bb << 9) + (s << 4) + (up << 1);
      *(float2*)(hn + nidx) = make_float2(h0v, h1v);
      *(float2*)(cn + nidx) = make_float2(c0, c1);
    }
  }
}

// ---------------- host ----------------
extern "C" void kernel_launch(void* const* d_in, const int* in_sizes, int n_in,
                              void* d_out, int out_size, void* d_ws, size_t ws_size,
                              hipStream_t stream) {
  const float* x = (const float*)d_in[0];
  const float* Wx0 = (const float*)d_in[1];
  const float* Wh0 = (const float*)d_in[2];
  const float* bx0 = (const float*)d_in[3];
  const float* bh0 = (const float*)d_in[4];
  const float* Wx1 = (const float*)d_in[5];
  const float* Wh1 = (const float*)d_in[6];
  const float* bx1 = (const float*)d_in[7];
  const float* bh1 = (const float*)d_in[8];

  char* ws = (char*)d_ws;
  size_t off = 0;
  auto alloc = [&](size_t b) { char* p = ws + off; off += (b + 255) & ~(size_t)255; return p; };
  f16* xg = (f16*)alloc(2ull * 16384 * 2048 * 2);      // 134 MB (reused both layers)
  f16* x_h = (f16*)alloc(16384ull * 512 * 2);
  f16* h0a = (f16*)alloc(16384ull * 1024 * 2);
  f16* Wx0h = (f16*)alloc(2ull * 2048 * 512 * 2);
  f16* Wh0h = (f16*)alloc(2ull * 2048 * 512 * 2);
  f16* Wx1h = (f16*)alloc(2ull * 2048 * 1024 * 2);
  f16* Wh1h = (f16*)alloc(2ull * 2048 * 512 * 2);
  float* bias0 = (float*)alloc(4096 * 4);
  float* bias1 = (float*)alloc(4096 * 4);
  const size_t RB = 2ull * 4 * 32 * 256 * 8;           // 512 KB per layer ring
  unsigned long long* ring0 = (unsigned long long*)alloc(RB);
  unsigned long long* ring1 = (unsigned long long*)alloc(RB);
  if (off > ws_size) return;  // needs ~207 MB of workspace

  float* outp = (float*)d_out;
  float* hn = outp + 16384ull * 1024;
  float* cn = hn + 4ull * 32 * 512;

  // clear ring tags (stale tags from a previous replay would alias epochs)
  hipMemsetAsync(ring0, 0, 2 * RB, stream);

  f2h_kernel<<<dim3(2097152 / 256), 256, 0, stream>>>(x, x_h, 2097152);
  f2h_kernel<<<dim3(524288 / 256), 256, 0, stream>>>(Wx0, Wx0h, 524288);
  f2h_kernel<<<dim3(524288 / 256), 256, 0, stream>>>(Wh0, Wh0h, 524288);
  f2h_kernel<<<dim3(1048576 / 256), 256, 0, stream>>>(Wx1, Wx1h, 1048576);
  f2h_kernel<<<dim3(524288 / 256), 256, 0, stream>>>(Wh1, Wh1h, 524288);
  bias_kernel<<<16, 256, 0, stream>>>(bx0, bh0, bias0, 4096);
  bias_kernel<<<16, 256, 0, stream>>>(bx1, bh1, bias1, 4096);

  dim3 g(128, 32);
  gemm_xg<<<g, 256, 0, stream>>>(x_h, Wx0h, bias0, xg, 512);
  lstm_scan<<<64, 256, 0, stream>>>(Wh0h, xg, ring0, h0a, nullptr, hn, cn, 0);
  gemm_xg<<<g, 256, 0, stream>>>(h0a, Wx1h, bias1, xg, 1024);
  lstm_scan<<<64, 256, 0, stream>>>(Wh1h, xg, ring1, nullptr, outp, hn, cn, 1);
}